// Round 13
// baseline (523.466 us; speedup 1.0000x reference)
//
#include <hip/hip_runtime.h>
#include <hip/hip_bf16.h>

#define D 64

typedef _Float16 f16;
typedef _Float16 f16x4 __attribute__((ext_vector_type(4)));
typedef _Float16 f16x8 __attribute__((ext_vector_type(8)));
typedef float f32x4 __attribute__((ext_vector_type(4)));

__device__ __forceinline__ int sw7(int m, int k) {  // row stride 128 f16
    return (m << 7) + (((k >> 3) ^ (m & 7)) << 3) + (k & 7);
}
__device__ __forceinline__ int sw6(int m, int k) {  // row stride 64 f16
    return (m << 6) + ((((k >> 3) ^ (m & 7)) & 7) << 3) + (k & 7);
}

// ---------------------------------------------------------------------------
// Direct node-level CSR build: histogram -> hierarchical scan -> fill.
// (Replaces the 2-level bucket build: one less 12.8MB scatter+rescan pass.)
// ---------------------------------------------------------------------------
__global__ void nhist_kernel(const int* __restrict__ dst, int* __restrict__ deg, int E)
{
    int e = blockIdx.x * 256 + threadIdx.x;
    if (e < E) atomicAdd(&deg[dst[e]], 1);
}

__global__ void scan_part(const int* __restrict__ deg, int* __restrict__ part, int N)
{
    __shared__ int red[256];
    int b = blockIdx.x, t = threadIdx.x;
    int base = b * 1024 + t * 4;
    int s = 0;
#pragma unroll
    for (int u = 0; u < 4; ++u) { int i = base + u; if (i < N) s += deg[i]; }
    red[t] = s; __syncthreads();
    for (int w = 128; w > 0; w >>= 1) {
        if (t < w) red[t] += red[t + w];
        __syncthreads();
    }
    if (t == 0) part[b] = red[0];
}

__global__ void scan_mid(int* __restrict__ part, int B)
{
    if (threadIdx.x == 0) {
        int run = 0;
        for (int b = 0; b < B; ++b) { int v = part[b]; part[b] = run; run += v; }
    }
}

__global__ void scan_out(const int* __restrict__ deg, const int* __restrict__ part,
                         int* __restrict__ cursor, int N)
{
    __shared__ int lds[256];
    int b = blockIdx.x, t = threadIdx.x;
    int base = b * 1024 + t * 4;
    int dv[4]; int s = 0;
#pragma unroll
    for (int u = 0; u < 4; ++u) { int i = base + u; dv[u] = (i < N) ? deg[i] : 0; s += dv[u]; }
    lds[t] = s; __syncthreads();
    for (int d2 = 1; d2 < 256; d2 <<= 1) {
        int v = (t >= d2) ? lds[t - d2] : 0;
        __syncthreads();
        lds[t] += v;
        __syncthreads();
    }
    int run = part[b] + lds[t] - s;  // exclusive prefix
#pragma unroll
    for (int u = 0; u < 4; ++u) {
        int i = base + u;
        if (i < N) cursor[i] = run;
        run += dv[u];
    }
}

__global__ void fill_kernel(const int* __restrict__ dst, const int* __restrict__ src,
                            int* __restrict__ cursor, int2* __restrict__ eix2, int E)
{
    int e = blockIdx.x * 256 + threadIdx.x;
    if (e < E) {
        int d = dst[e];
        int p = atomicAdd(&cursor[d], 1);
        eix2[p] = make_int2(src[e], d);
    }
}

// ---------------------------------------------------------------------------
// Edge MLP via MFMA. All tile inputs (edge idx, src row, dst row, boundary
// dsts) register-prefetched a full tile ahead -> stage phase is pure reg->LDS,
// barrier(1) waits on no global load. GEMM1 A = plain f16; xs exact f32 in
// LDS. wb1 in VGPRs, We2 in LDS. Segsum parallelized over 2 waves (half-
// boundary runs flushed via atomicAdd). Contrib stride 66: write bank =
// (2m+col)%32 -> 2-way (free), was 4-way at stride 65. 4 blocks/CU.
// ---------------------------------------------------------------------------
__global__ __launch_bounds__(256, 4) void edge_mfma_kernel(
    const float* __restrict__ x,
    const float* __restrict__ We1, const float* __restrict__ be1,
    const float* __restrict__ We2, const float* __restrict__ be2,
    const int2* __restrict__ eix,
    float* __restrict__ hneigh, int N, int E, int T)
{
    __shared__ __attribute__((aligned(16))) f16 Ahi[32 * 128];   // 8KB
    __shared__ __attribute__((aligned(16))) float Xs[32 * 68];   // 8.5KB
    __shared__ __attribute__((aligned(16))) f16 Hbuf[32 * 64];   // 4KB
    __shared__ __attribute__((aligned(16))) f16 W2s[64 * 64];    // 8KB
    __shared__ __attribute__((aligned(16))) float Contrib[32 * 66]; // 8.25KB
    __shared__ int edstS[32];
    __shared__ int prevD_, nextD_;

    const int tid = threadIdx.x;
    const int w = tid >> 6;
    const int lane = tid & 63;
    const int l15 = lane & 15;
    const int quad = lane >> 4;
    const int m0 = (w & 1) * 16;        // edge strip within tile
    const int nh = (w >> 1) * 32;       // feature half

    // GEMM1 weights in registers (32 VGPRs).
    f16x8 wb1[4][2];
#pragma unroll
    for (int kt = 0; kt < 4; ++kt)
#pragma unroll
        for (int nf = 0; nf < 2; ++nf) {
            int n = nh + nf * 16 + l15;
#pragma unroll
            for (int j = 0; j < 8; ++j)
                wb1[kt][nf][j] = (f16)We1[(kt * 32 + quad * 8 + j) * 64 + n];
        }
    // GEMM2 weights in LDS.
    {
        int n = tid & 63;
        int kb2 = (tid >> 6) * 16;
        for (int kk = 0; kk < 16; ++kk) {
            int k = kb2 + kk;
            W2s[sw6(n, k)] = (f16)We2[k * 64 + n];
        }
    }

    const float b1v0 = be1[nh + l15], b1v1 = be1[nh + 16 + l15];
    const float b2v0 = be2[nh + l15], b2v1 = be2[nh + 16 + l15];

    const int i = tid >> 3;   // staging: edge in tile
    const int c = tid & 7;    // staging: 8-feature chunk

    // prologue: prefetch tile0 (edge idx + src row + dst row + boundary dsts)
    int2 pe;
    float4 pf0, pf1, pf2, pf3;
    int pPrev = -2, pNext = -2;
    {
        int e0 = blockIdx.x * 32;
        int ei = min(e0 + i, E - 1);
        pe = eix[ei];
        const float* ps = x + (size_t)pe.x * D + c * 8;
        const float* pd = x + (size_t)pe.y * D + c * 8;
        pf0 = *(const float4*)ps;
        pf1 = *(const float4*)(ps + 4);
        pf2 = *(const float4*)pd;
        pf3 = *(const float4*)(pd + 4);
        if (tid == 0  && e0 > 0)          pPrev = eix[e0 - 1].y;
        if (tid == 64 && e0 + 32 < E)     pNext = eix[e0 + 32].y;
    }

    for (int tile = blockIdx.x; tile < T; tile += gridDim.x) {
        const int e0 = tile * 32;

        // ---- stage: pure reg -> LDS (no global loads) ----
        {
            f16x8 sh, dh;
            sh[0] = (f16)pf0.x; sh[1] = (f16)pf0.y; sh[2] = (f16)pf0.z; sh[3] = (f16)pf0.w;
            sh[4] = (f16)pf1.x; sh[5] = (f16)pf1.y; sh[6] = (f16)pf1.z; sh[7] = (f16)pf1.w;
            dh[0] = (f16)pf2.x; dh[1] = (f16)pf2.y; dh[2] = (f16)pf2.z; dh[3] = (f16)pf2.w;
            dh[4] = (f16)pf3.x; dh[5] = (f16)pf3.y; dh[6] = (f16)pf3.z; dh[7] = (f16)pf3.w;
            *(f16x8*)&Ahi[sw7(i, c * 8)] = sh;
            *(f16x8*)&Ahi[sw7(i, 64 + c * 8)] = dh;
            *(float4*)&Xs[i * 68 + c * 8] = pf0;
            *(float4*)&Xs[i * 68 + c * 8 + 4] = pf1;
            if (c == 0) edstS[i] = (e0 + i < E) ? pe.y : N;
            if (tid == 0)  prevD_ = pPrev;
            if (tid == 64) nextD_ = pNext;
        }
        __syncthreads();  // (1)

        // ---- prefetch next tile (full tile of latency to cover) ----
        {
            int tn = tile + gridDim.x;
            if (tn < T) {
                int ne0 = tn * 32;
                int ei = min(ne0 + i, E - 1);
                pe = eix[ei];
                const float* ps = x + (size_t)pe.x * D + c * 8;
                const float* pd = x + (size_t)pe.y * D + c * 8;
                pf0 = *(const float4*)ps;
                pf1 = *(const float4*)(ps + 4);
                pf2 = *(const float4*)pd;
                pf3 = *(const float4*)(pd + 4);
                pPrev = -2; pNext = -2;
                if (tid == 0  && ne0 > 0)      pPrev = eix[ne0 - 1].y;
                if (tid == 64 && ne0 + 32 < E) pNext = eix[ne0 + 32].y;
            }
        }

        // ---- GEMM1: [32,128]@[128,64], A single f16 ----
        f32x4 c0 = {0.f, 0.f, 0.f, 0.f}, c1 = {0.f, 0.f, 0.f, 0.f};
#pragma unroll
        for (int kt = 0; kt < 4; ++kt) {
            int k = kt * 32 + quad * 8;
            f16x8 ah = *(const f16x8*)&Ahi[sw7(m0 + l15, k)];
            c0 = __builtin_amdgcn_mfma_f32_16x16x32_f16(ah, wb1[kt][0], c0, 0, 0, 0);
            c1 = __builtin_amdgcn_mfma_f32_16x16x32_f16(ah, wb1[kt][1], c1, 0, 0, 0);
        }

#pragma unroll
        for (int i2 = 0; i2 < 4; ++i2) {
            int m = m0 + quad * 4 + i2;
            Hbuf[sw6(m, nh + l15)]      = (f16)fmaxf(c0[i2] + b1v0, 0.f);
            Hbuf[sw6(m, nh + 16 + l15)] = (f16)fmaxf(c1[i2] + b1v1, 0.f);
        }
        __syncthreads();  // (2)

        // ---- GEMM2: [32,64]@[64,64] ----
        f32x4 d0 = {0.f, 0.f, 0.f, 0.f}, d1 = {0.f, 0.f, 0.f, 0.f};
#pragma unroll
        for (int kt = 0; kt < 2; ++kt) {
            int k = kt * 32 + quad * 8;
            f16x8 ah = *(const f16x8*)&Hbuf[sw6(m0 + l15, k)];
            f16x8 b0 = *(const f16x8*)&W2s[sw6(nh + l15, k)];
            f16x8 b1 = *(const f16x8*)&W2s[sw6(nh + 16 + l15, k)];
            d0 = __builtin_amdgcn_mfma_f32_16x16x32_f16(ah, b0, d0, 0, 0, 0);
            d1 = __builtin_amdgcn_mfma_f32_16x16x32_f16(ah, b1, d1, 0, 0, 0);
        }

        // ---- contrib = xs * (d + be2), xs exact f32 from LDS ----
#pragma unroll
        for (int i2 = 0; i2 < 4; ++i2) {
            int m = m0 + quad * 4 + i2;
            float xs0 = Xs[m * 68 + nh + l15];
            float xs1 = Xs[m * 68 + nh + 16 + l15];
            Contrib[m * 66 + nh + l15]      = (d0[i2] + b2v0) * xs0;
            Contrib[m * 66 + nh + 16 + l15] = (d1[i2] + b2v1) * xs1;
        }
        __syncthreads();  // (3)

        // ---- segmented sum, 2 waves (16 rows each); boundary runs atomic ----
        if (tid < 128) {
            int j = tid & 63;
            int h = tid >> 6;
            int base = h * 16;
            int prevB = (h == 0) ? prevD_ : edstS[15];
            int nextB = (h == 0) ? edstS[16] : nextD_;
            float a = 0.f;
            int cur = edstS[base];
            int runStart = base;
#pragma unroll
            for (int ii = base; ii < base + 16; ++ii) {
                a += Contrib[ii * 66 + j];
                int nxt = (ii < base + 15) ? edstS[ii + 1] : -3;  // force flush
                if (nxt != cur) {
                    bool firstRun = (runStart == base);
                    bool lastRun = (ii == base + 15);
                    bool complete = (!firstRun || prevB != cur) &&
                                    (!lastRun || nextB != cur);
                    if (complete) hneigh[(size_t)cur * D + j] = a;
                    else atomicAdd(&hneigh[(size_t)cur * D + j], a);
                    a = 0.f; cur = nxt; runStart = ii + 1;
                }
            }
        }
        __syncthreads();  // (4)
    }
}

// ---------------------------------------------------------------------------
// Node MLP via MFMA, weights in VGPR fragments, 2-term split.
// ---------------------------------------------------------------------------
__global__ __launch_bounds__(256, 4) void node_mfma_kernel(
    float* __restrict__ h,
    const float* __restrict__ Wn, const float* __restrict__ bn,
    const float* __restrict__ Wg, const float* __restrict__ bg,
    float* __restrict__ gate, int N, int T)
{
    __shared__ __attribute__((aligned(16))) f16 ANhi[64 * 64];
    __shared__ __attribute__((aligned(16))) f16 ANlo[64 * 64];

    const int tid = threadIdx.x;
    const int w = tid >> 6;
    const int lane = tid & 63;
    const int l15 = lane & 15;
    const int quad = lane >> 4;
    const int m0 = w * 16;

    f16x8 wn[2][4];
#pragma unroll
    for (int kt = 0; kt < 2; ++kt)
#pragma unroll
        for (int nf = 0; nf < 4; ++nf) {
            int n = nf * 16 + l15;
#pragma unroll
            for (int j = 0; j < 8; ++j)
                wn[kt][nf][j] = (f16)Wn[(kt * 32 + quad * 8 + j) * 64 + n];
        }

    float bnv[4], wgv[4];
#pragma unroll
    for (int nt = 0; nt < 4; ++nt) {
        bnv[nt] = bn[nt * 16 + l15];
        wgv[nt] = Wg[nt * 16 + l15];
    }
    const float bgv = bg[0];

    for (int tile = blockIdx.x; tile < T; tile += gridDim.x) {
        const int t0 = tile * 64;

        {
            int i = tid >> 2;
            int q = tid & 3;
            int node = min(t0 + i, N - 1);
            const float* p = h + (size_t)node * D + q * 16;
#pragma unroll
            for (int r = 0; r < 4; ++r) {
                float4 v = *(const float4*)(p + r * 4);
                int k = q * 16 + r * 4;
                f16x4 hv, lv;
                hv[0] = (f16)v.x; lv[0] = (f16)(v.x - (float)hv[0]);
                hv[1] = (f16)v.y; lv[1] = (f16)(v.y - (float)hv[1]);
                hv[2] = (f16)v.z; lv[2] = (f16)(v.z - (float)hv[2]);
                hv[3] = (f16)v.w; lv[3] = (f16)(v.w - (float)hv[3]);
                *(f16x4*)&ANhi[sw6(i, k)] = hv;
                *(f16x4*)&ANlo[sw6(i, k)] = lv;
            }
        }
        __syncthreads();

        f32x4 cacc[4] = {{0.f,0.f,0.f,0.f},{0.f,0.f,0.f,0.f},{0.f,0.f,0.f,0.f},{0.f,0.f,0.f,0.f}};
#pragma unroll
        for (int kt = 0; kt < 2; ++kt) {
            int k = kt * 32 + quad * 8;
            f16x8 ah = *(const f16x8*)&ANhi[sw6(m0 + l15, k)];
            f16x8 al = *(const f16x8*)&ANlo[sw6(m0 + l15, k)];
#pragma unroll
            for (int nf = 0; nf < 4; ++nf) {
                cacc[nf] = __builtin_amdgcn_mfma_f32_16x16x32_f16(ah, wn[kt][nf], cacc[nf], 0, 0, 0);
                cacc[nf] = __builtin_amdgcn_mfma_f32_16x16x32_f16(al, wn[kt][nf], cacc[nf], 0, 0, 0);
            }
        }
        __syncthreads();

        float gpart[4] = {0.f, 0.f, 0.f, 0.f};
#pragma unroll
        for (int nt = 0; nt < 4; ++nt) {
            int n = nt * 16 + l15;
#pragma unroll
            for (int i2 = 0; i2 < 4; ++i2) {
                int m = t0 + m0 + quad * 4 + i2;
                float v = fmaxf(cacc[nt][i2] + bnv[nt], 0.f);
                if (m < N) h[(size_t)m * D + n] = v;
                gpart[i2] += v * wgv[nt];
            }
        }
#pragma unroll
        for (int s = 1; s < 16; s <<= 1) {
#pragma unroll
            for (int i2 = 0; i2 < 4; ++i2) gpart[i2] += __shfl_xor(gpart[i2], s);
        }
        if (l15 == 0) {
#pragma unroll
            for (int i2 = 0; i2 < 4; ++i2) {
                int m = t0 + m0 + quad * 4 + i2;
                if (m < N) gate[m] = gpart[i2] + bgv;
            }
        }
    }
}

// ---------------------------------------------------------------------------
// Pool: one block per graph; softmax over gates, weighted sum, classifier.
// ---------------------------------------------------------------------------
__global__ __launch_bounds__(256) void pool_kernel(
    const float* __restrict__ h2,
    const float* __restrict__ gate,
    const int* __restrict__ gid,
    const float* __restrict__ Wfc, const float* __restrict__ bfc,
    float* __restrict__ out, int N, int C)
{
    int g = blockIdx.x;
    int tid = threadIdx.x;

    int lo = 0, hi = N;
    while (lo < hi) { int mid = (lo + hi) >> 1; if (gid[mid] < g) lo = mid + 1; else hi = mid; }
    int s = lo;
    hi = N;
    while (lo < hi) { int mid = (lo + hi) >> 1; if (gid[mid] < g + 1) lo = mid + 1; else hi = mid; }
    int e = lo;

    __shared__ float red[256];
    __shared__ float accs[4][D];
    __shared__ float dens[4];

    float m = -INFINITY;
    for (int i = s + tid; i < e; i += 256) m = fmaxf(m, gate[i]);
    red[tid] = m;
    __syncthreads();
    for (int w = 128; w > 0; w >>= 1) {
        if (tid < w) red[tid] = fmaxf(red[tid], red[tid + w]);
        __syncthreads();
    }
    float gmax = red[0];
    __syncthreads();

    int f = tid & (D - 1);
    int grp = tid >> 6;
    float acc = 0.0f, den = 0.0f;
    for (int i = s + grp; i < e; i += 4) {
        float w = expf(gate[i] - gmax);
        acc += w * h2[(size_t)i * D + f];
        if (f == 0) den += w;
    }
    accs[grp][f] = acc;
    if (f == 0) dens[grp] = den;
    __syncthreads();

    if (tid < D) {
        float p = accs[0][tid] + accs[1][tid] + accs[2][tid] + accs[3][tid];
        float dn = dens[0] + dens[1] + dens[2] + dens[3];
        p = (e > s) ? (p / dn) : 0.0f;
        red[tid] = p;
    }
    __syncthreads();

    if (tid < C) {
        float o = bfc[tid];
#pragma unroll
        for (int k = 0; k < D; ++k) o += red[k] * Wfc[k * C + tid];
        out[g * C + tid] = o;
    }
}

extern "C" void kernel_launch(void* const* d_in, const int* in_sizes, int n_in,
                              void* d_out, int out_size, void* d_ws, size_t ws_size,
                              hipStream_t stream) {
    const float* x   = (const float*)d_in[0];
    const float* We1 = (const float*)d_in[1];
    const float* be1 = (const float*)d_in[2];
    const float* We2 = (const float*)d_in[3];
    const float* be2 = (const float*)d_in[4];
    const float* Wn  = (const float*)d_in[5];
    const float* bn  = (const float*)d_in[6];
    const float* Wg  = (const float*)d_in[7];
    const float* bg  = (const float*)d_in[8];
    const float* Wfc = (const float*)d_in[9];
    const float* bfc = (const float*)d_in[10];
    const int* src = (const int*)d_in[11];
    const int* dst = (const int*)d_in[12];
    const int* gid = (const int*)d_in[13];

    const int N = in_sizes[0] / D;
    const int E = in_sizes[11];
    const int C = 10;
    const int G = out_size / C;

    // workspace: eix2 | hneigh(+sentinel) | gate | deg | cursor | part
    int2*  eix2   = (int2*)d_ws;                          // [E]        12.8MB
    float* hneigh = (float*)(eix2 + E);                   // [(N+1)*64] 25.6MB
    float* gate   = hneigh + (size_t)(N + 1) * D;         // [N]
    int*   deg    = (int*)(gate + N);                     // [N]
    int*   cursor = deg + N;                              // [N]
    int*   part   = cursor + N;                           // [128]
    float* outp   = (float*)d_out;

    const int Bp = (N + 1023) / 1024;
    const int Te = (E + 31) / 32;
    const int Tn = (N + 63) / 64;

    hipMemsetAsync(deg, 0, (size_t)N * sizeof(int), stream);

    nhist_kernel<<<(E + 255) / 256, 256, 0, stream>>>(dst, deg, E);
    scan_part<<<Bp, 256, 0, stream>>>(deg, part, N);
    scan_mid<<<1, 64, 0, stream>>>(part, Bp);
    scan_out<<<Bp, 256, 0, stream>>>(deg, part, cursor, N);
    fill_kernel<<<(E + 255) / 256, 256, 0, stream>>>(dst, src, cursor, eix2, E);

    hipMemsetAsync(hneigh, 0, (size_t)(N + 1) * D * sizeof(float), stream);

    edge_mfma_kernel<<<1024, 256, 0, stream>>>(x, We1, be1, We2, be2,
                                               eix2, hneigh, N, E, Te);
    node_mfma_kernel<<<1024, 256, 0, stream>>>(hneigh, Wn, bn, Wg, bg, gate, N, Tn);
    pool_kernel<<<G, 256, 0, stream>>>(hneigh, gate, gid, Wfc, bfc, outp, N, C);
}